// Round 1
// baseline (536.001 us; speedup 1.0000x reference)
//
#include <hip/hip_runtime.h>
#include <hip/hip_bf16.h>

#define N_NODES 50000
#define BATCH   4
#define N_EDGES 500000
#define H_SIZE  64

// One 64-lane wave per edge. Lane i owns feature i.
//   out[b, src, i] += w * H[b, dst, i]
// Edge record (src_f, dst_f, w) is wave-uniform -> broadcast from cache.
// H row read is 256B contiguous (fully coalesced); atomics are 4B/lane
// contiguous within a 256B segment.
__global__ __launch_bounds__(256) void neighbor_agg_kernel(
    const float* __restrict__ H,
    const float* __restrict__ ew,
    float* __restrict__ out)
{
    const long long gid  = (long long)blockIdx.x * blockDim.x + threadIdx.x;
    const long long wave = gid >> 6;                  // edge index in [0, B*E)
    const int lane = threadIdx.x & 63;
    if (wave >= (long long)BATCH * N_EDGES) return;

    const int b = (int)(wave / N_EDGES);

    const long long ebase = wave * 3;
    const float sf = ew[ebase + 0];
    const float df = ew[ebase + 1];
    const float w  = ew[ebase + 2];
    const int src = (int)sf;
    const int dst = (int)df;

    const long long hbase = ((long long)b * N_NODES + dst) * H_SIZE;
    const long long obase = ((long long)b * N_NODES + src) * H_SIZE;

    const float v = w * H[hbase + lane];
    atomicAdd(&out[obase + lane], v);
}

extern "C" void kernel_launch(void* const* d_in, const int* in_sizes, int n_in,
                              void* d_out, int out_size, void* d_ws, size_t ws_size,
                              hipStream_t stream) {
    const float* H  = (const float*)d_in[0];   // (B, N, 64) fp32
    const float* ew = (const float*)d_in[1];   // (B, E, 3) fp32
    float* out = (float*)d_out;                // (B, N, 64) fp32

    // Harness poisons d_out with 0xAA before every timed launch -> zero it.
    hipMemsetAsync(out, 0, (size_t)out_size * sizeof(float), stream);

    const long long total_threads = (long long)BATCH * N_EDGES * 64;
    const int block = 256;
    const long long grid = (total_threads + block - 1) / block;
    neighbor_agg_kernel<<<(dim3)(unsigned)grid, block, 0, stream>>>(H, ew, out);
}

// Round 3
// 524.099 us; speedup vs baseline: 1.0227x; 1.0227x over previous
//
#include <hip/hip_runtime.h>
#include <hip/hip_bf16.h>

#define N_NODES 50000
#define BATCH   4
#define N_EDGES 500000
#define H_SIZE  64

#define NSEG   (BATCH * N_NODES)        // 200,000 segments (b, src)
#define NEDGE  (BATCH * N_EDGES)        // 2,000,000 edges
#define SCAN_B 1024
#define NB1    ((NSEG + SCAN_B - 1) / SCAN_B)   // 196 scan blocks

// ---------- Zeroing (NO hipMemsetAsync inside kernel_launch: a memset
// node may be dropped/unsupported under graph capture; a kernel always
// captures correctly) ----------
__global__ __launch_bounds__(256) void zero_kernel(int* __restrict__ p, long long n)
{
    long long i = (long long)blockIdx.x * blockDim.x + threadIdx.x;
    if (i < n) p[i] = 0;
}

// ---------- Phase 1: per-segment histogram ----------
__global__ __launch_bounds__(256) void hist_kernel(
    const float* __restrict__ ew, int* __restrict__ cnt)
{
    long long e = (long long)blockIdx.x * blockDim.x + threadIdx.x;
    if (e >= NEDGE) return;
    int b = (int)(e / N_EDGES);
    int src = (int)ew[e * 3];
    src = min(max(src, 0), N_NODES - 1);
    atomicAdd(&cnt[b * N_NODES + src], 1);
}

// ---------- Phase 2: exclusive scan over 200k counts ----------
__global__ __launch_bounds__(SCAN_B) void scan1_kernel(
    const int* __restrict__ cnt, int* __restrict__ offs, int* __restrict__ bsum)
{
    __shared__ int sm[SCAN_B];
    int i = blockIdx.x * SCAN_B + threadIdx.x;
    int v = (i < NSEG) ? cnt[i] : 0;
    sm[threadIdx.x] = v;
    __syncthreads();
    for (int off = 1; off < SCAN_B; off <<= 1) {
        int t = (threadIdx.x >= off) ? sm[threadIdx.x - off] : 0;
        __syncthreads();
        sm[threadIdx.x] += t;
        __syncthreads();
    }
    if (i < NSEG) offs[i] = sm[threadIdx.x] - v;        // exclusive
    if (threadIdx.x == SCAN_B - 1) bsum[blockIdx.x] = sm[SCAN_B - 1];
}

__global__ __launch_bounds__(256) void scan2_kernel(int* __restrict__ bsum)
{
    __shared__ int sm[256];
    int v = (threadIdx.x < NB1) ? bsum[threadIdx.x] : 0;
    sm[threadIdx.x] = v;
    __syncthreads();
    for (int off = 1; off < 256; off <<= 1) {
        int t = (threadIdx.x >= off) ? sm[threadIdx.x - off] : 0;
        __syncthreads();
        sm[threadIdx.x] += t;
        __syncthreads();
    }
    if (threadIdx.x < NB1) bsum[threadIdx.x] = sm[threadIdx.x] - v;  // exclusive
}

__global__ __launch_bounds__(256) void scan3_kernel(
    int* __restrict__ offs, const int* __restrict__ bsum)
{
    int i = blockIdx.x * blockDim.x + threadIdx.x;
    if (i < NSEG) offs[i] += bsum[i >> 10];
}

// ---------- Phase 3: scatter edges into CSR buckets ----------
// atomicAdd turns offs into "end" pointers; gather recovers start = end - cnt.
// pos is clamped so no input/state pathology can ever write outside d_ws.
__global__ __launch_bounds__(256) void scatter_kernel(
    const float* __restrict__ ew, int* __restrict__ offs,
    int* __restrict__ bdst, float* __restrict__ bw)
{
    long long e = (long long)blockIdx.x * blockDim.x + threadIdx.x;
    if (e >= NEDGE) return;
    int b = (int)(e / N_EDGES);
    long long eb = e * 3;
    int src = (int)ew[eb];
    int dst = (int)ew[eb + 1];
    float w = ew[eb + 2];
    src = min(max(src, 0), N_NODES - 1);
    int pos = atomicAdd(&offs[b * N_NODES + src], 1);
    pos = min(max(pos, 0), NEDGE - 1);   // defensive: never OOB
    bdst[pos] = dst;
    bw[pos] = w;
}

// ---------- Phase 4: gather. One wave per (b, node), lane = feature ----------
__global__ __launch_bounds__(256) void gather_kernel(
    const float* __restrict__ H, const int* __restrict__ cnt,
    const int* __restrict__ offs,  // holds segment END after scatter
    const int* __restrict__ bdst, const float* __restrict__ bw,
    float* __restrict__ out)
{
    long long gid = (long long)blockIdx.x * blockDim.x + threadIdx.x;
    long long seg = gid >> 6;
    int lane = threadIdx.x & 63;
    if (seg >= NSEG) return;

    int b = (int)(seg / N_NODES);
    int end = offs[seg];
    int deg = cnt[seg];
    int start = end - deg;
    start = min(max(start, 0), NEDGE);
    end   = min(max(end,   0), NEDGE);

    const float* Hb = H + (long long)b * N_NODES * H_SIZE;

    float acc = 0.0f;
    for (int i = start; i < end; ++i) {
        int dst = bdst[i];     // wave-uniform -> broadcast
        dst = min(max(dst, 0), N_NODES - 1);
        float w = bw[i];
        acc = fmaf(w, Hb[(long long)dst * H_SIZE + lane], acc);
    }
    out[seg * H_SIZE + lane] = acc;
}

// ---------- Fallback: atomic kernel (if ws too small) ----------
__global__ __launch_bounds__(256) void atomic_kernel(
    const float* __restrict__ H, const float* __restrict__ ew,
    float* __restrict__ out)
{
    const long long gid = (long long)blockIdx.x * blockDim.x + threadIdx.x;
    const long long wave = gid >> 6;
    const int lane = threadIdx.x & 63;
    if (wave >= (long long)NEDGE) return;
    const int b = (int)(wave / N_EDGES);
    const long long ebase = wave * 3;
    const int src = (int)ew[ebase + 0];
    const int dst = (int)ew[ebase + 1];
    const float w = ew[ebase + 2];
    const long long hbase = ((long long)b * N_NODES + dst) * H_SIZE;
    const long long obase = ((long long)b * N_NODES + src) * H_SIZE;
    atomicAdd(&out[obase + lane], w * H[hbase + lane]);
}

extern "C" void kernel_launch(void* const* d_in, const int* in_sizes, int n_in,
                              void* d_out, int out_size, void* d_ws, size_t ws_size,
                              hipStream_t stream) {
    const float* H  = (const float*)d_in[0];   // (B, N, 64) fp32
    const float* ew = (const float*)d_in[1];   // (B, E, 3) fp32
    float* out = (float*)d_out;                // (B, N, 64) fp32

    // Workspace layout (4B elems): cnt[NSEG] | offs[NSEG] | bsum[256] |
    //                              bdst[NEDGE] | bw[NEDGE]
    const size_t need = ((size_t)NSEG * 2 + 256 + (size_t)NEDGE * 2) * 4;

    if (ws_size < need) {
        // Fallback: atomic scatter version (zero out via kernel, not memset).
        long long n = out_size;
        zero_kernel<<<(unsigned)((n + 255) / 256), 256, 0, stream>>>((int*)out, n);
        const long long total = (long long)NEDGE * 64;
        atomic_kernel<<<(unsigned)((total + 255) / 256), 256, 0, stream>>>(H, ew, out);
        return;
    }

    int* cnt  = (int*)d_ws;
    int* offs = cnt + NSEG;
    int* bsum = offs + NSEG;
    int* bdst = bsum + 256;
    float* bw = (float*)(bdst + NEDGE);

    zero_kernel<<<(NSEG + 255) / 256, 256, 0, stream>>>(cnt, NSEG);

    hist_kernel<<<(NEDGE + 255) / 256, 256, 0, stream>>>(ew, cnt);
    scan1_kernel<<<NB1, SCAN_B, 0, stream>>>(cnt, offs, bsum);
    scan2_kernel<<<1, 256, 0, stream>>>(bsum);
    scan3_kernel<<<(NSEG + 255) / 256, 256, 0, stream>>>(offs, bsum);
    scatter_kernel<<<(NEDGE + 255) / 256, 256, 0, stream>>>(ew, offs, bdst, bw);

    const long long gthreads = (long long)NSEG * 64;
    gather_kernel<<<(unsigned)((gthreads + 255) / 256), 256, 0, stream>>>(
        H, cnt, offs, bdst, bw, out);
}

// Round 4
// 436.954 us; speedup vs baseline: 1.2267x; 1.1994x over previous
//
#include <hip/hip_runtime.h>
#include <hip/hip_bf16.h>

#define N_NODES 50000
#define BATCH   4
#define N_EDGES 500000
#define H_SIZE  64

#define NSEG   (BATCH * N_NODES)        // 200,000 segments (b, src)
#define NEDGE  (BATCH * N_EDGES)        // 2,000,000 edges
#define SCAN_B 1024
#define NB1    ((NSEG + SCAN_B - 1) / SCAN_B)   // 196 scan blocks

// ---------- Zeroing (kernel, NOT hipMemsetAsync: memset nodes proved
// unreliable under graph capture in R2 — int view of 0xAA poison broke
// the histogram and caused OOB scatter) ----------
__global__ __launch_bounds__(256) void zero_kernel(int* __restrict__ p, long long n)
{
    long long i = (long long)blockIdx.x * blockDim.x + threadIdx.x;
    if (i < n) p[i] = 0;
}

// ---------- Phase 1: per-segment histogram ----------
__global__ __launch_bounds__(256) void hist_kernel(
    const float* __restrict__ ew, int* __restrict__ cnt)
{
    long long e = (long long)blockIdx.x * blockDim.x + threadIdx.x;
    if (e >= NEDGE) return;
    int b = (int)(e / N_EDGES);
    int src = (int)ew[e * 3];
    src = min(max(src, 0), N_NODES - 1);
    atomicAdd(&cnt[b * N_NODES + src], 1);
}

// ---------- Phase 2: exclusive scan over 200k counts ----------
__global__ __launch_bounds__(SCAN_B) void scan1_kernel(
    const int* __restrict__ cnt, int* __restrict__ offs, int* __restrict__ bsum)
{
    __shared__ int sm[SCAN_B];
    int i = blockIdx.x * SCAN_B + threadIdx.x;
    int v = (i < NSEG) ? cnt[i] : 0;
    sm[threadIdx.x] = v;
    __syncthreads();
    for (int off = 1; off < SCAN_B; off <<= 1) {
        int t = (threadIdx.x >= off) ? sm[threadIdx.x - off] : 0;
        __syncthreads();
        sm[threadIdx.x] += t;
        __syncthreads();
    }
    if (i < NSEG) offs[i] = sm[threadIdx.x] - v;        // exclusive
    if (threadIdx.x == SCAN_B - 1) bsum[blockIdx.x] = sm[SCAN_B - 1];
}

__global__ __launch_bounds__(256) void scan2_kernel(int* __restrict__ bsum)
{
    __shared__ int sm[256];
    int v = (threadIdx.x < NB1) ? bsum[threadIdx.x] : 0;
    sm[threadIdx.x] = v;
    __syncthreads();
    for (int off = 1; off < 256; off <<= 1) {
        int t = (threadIdx.x >= off) ? sm[threadIdx.x - off] : 0;
        __syncthreads();
        sm[threadIdx.x] += t;
        __syncthreads();
    }
    if (threadIdx.x < NB1) bsum[threadIdx.x] = sm[threadIdx.x] - v;  // exclusive
}

__global__ __launch_bounds__(256) void scan3_kernel(
    int* __restrict__ offs, const int* __restrict__ bsum)
{
    int i = blockIdx.x * blockDim.x + threadIdx.x;
    if (i < NSEG) offs[i] += bsum[i >> 10];
}

// ---------- Phase 3: scatter edges into CSR buckets ----------
// One packed int2{dst, bits(w)} per edge: a single 8B write to ONE random
// cache line (vs two lines for split bdst/bw arrays).
__global__ __launch_bounds__(256) void scatter_kernel(
    const float* __restrict__ ew, int* __restrict__ offs,
    int2* __restrict__ pair)
{
    long long e = (long long)blockIdx.x * blockDim.x + threadIdx.x;
    if (e >= NEDGE) return;
    int b = (int)(e / N_EDGES);
    long long eb = e * 3;
    int src = (int)ew[eb];
    int dst = (int)ew[eb + 1];
    float w = ew[eb + 2];
    src = min(max(src, 0), N_NODES - 1);
    int pos = atomicAdd(&offs[b * N_NODES + src], 1);
    pos = min(max(pos, 0), NEDGE - 1);   // defensive: never OOB
    int2 v; v.x = dst; v.y = __float_as_int(w);
    pair[pos] = v;
}

// ---------- Phase 4: gather. One wave per (b, node), lane = feature ----------
// Unrolled x8: issue 8 independent pair loads, then 8 independent H-row
// loads, before accumulating -> MLP ~8 outstanding loads per wave instead
// of a serial 1-deep dependent chain (R3 was latency-bound at 16% HBM).
__global__ __launch_bounds__(256) void gather_kernel(
    const float* __restrict__ H, const int* __restrict__ cnt,
    const int* __restrict__ offs,  // holds segment END after scatter
    const int2* __restrict__ pair,
    float* __restrict__ out)
{
    long long gid = (long long)blockIdx.x * blockDim.x + threadIdx.x;
    long long seg = gid >> 6;
    int lane = threadIdx.x & 63;
    if (seg >= NSEG) return;

    int b = (int)(seg / N_NODES);
    int end = offs[seg];
    int deg = cnt[seg];
    int start = end - deg;
    start = min(max(start, 0), NEDGE);
    end   = min(max(end,   0), NEDGE);

    const float* Hb = H + (long long)b * N_NODES * H_SIZE;

    float acc0 = 0.0f, acc1 = 0.0f;
    int i = start;
    for (; i + 8 <= end; i += 8) {
        int2 p0 = pair[i + 0], p1 = pair[i + 1], p2 = pair[i + 2], p3 = pair[i + 3];
        int2 p4 = pair[i + 4], p5 = pair[i + 5], p6 = pair[i + 6], p7 = pair[i + 7];
        int d0 = min(max(p0.x, 0), N_NODES - 1);
        int d1 = min(max(p1.x, 0), N_NODES - 1);
        int d2 = min(max(p2.x, 0), N_NODES - 1);
        int d3 = min(max(p3.x, 0), N_NODES - 1);
        int d4 = min(max(p4.x, 0), N_NODES - 1);
        int d5 = min(max(p5.x, 0), N_NODES - 1);
        int d6 = min(max(p6.x, 0), N_NODES - 1);
        int d7 = min(max(p7.x, 0), N_NODES - 1);
        float h0 = Hb[(long long)d0 * H_SIZE + lane];
        float h1 = Hb[(long long)d1 * H_SIZE + lane];
        float h2 = Hb[(long long)d2 * H_SIZE + lane];
        float h3 = Hb[(long long)d3 * H_SIZE + lane];
        float h4 = Hb[(long long)d4 * H_SIZE + lane];
        float h5 = Hb[(long long)d5 * H_SIZE + lane];
        float h6 = Hb[(long long)d6 * H_SIZE + lane];
        float h7 = Hb[(long long)d7 * H_SIZE + lane];
        acc0 = fmaf(__int_as_float(p0.y), h0, acc0);
        acc1 = fmaf(__int_as_float(p1.y), h1, acc1);
        acc0 = fmaf(__int_as_float(p2.y), h2, acc0);
        acc1 = fmaf(__int_as_float(p3.y), h3, acc1);
        acc0 = fmaf(__int_as_float(p4.y), h4, acc0);
        acc1 = fmaf(__int_as_float(p5.y), h5, acc1);
        acc0 = fmaf(__int_as_float(p6.y), h6, acc0);
        acc1 = fmaf(__int_as_float(p7.y), h7, acc1);
    }
    for (; i < end; ++i) {
        int2 p = pair[i];
        int d = min(max(p.x, 0), N_NODES - 1);
        acc0 = fmaf(__int_as_float(p.y), Hb[(long long)d * H_SIZE + lane], acc0);
    }
    out[seg * H_SIZE + lane] = acc0 + acc1;
}

// ---------- Fallback: atomic kernel (if ws too small) ----------
__global__ __launch_bounds__(256) void atomic_kernel(
    const float* __restrict__ H, const float* __restrict__ ew,
    float* __restrict__ out)
{
    const long long gid = (long long)blockIdx.x * blockDim.x + threadIdx.x;
    const long long wave = gid >> 6;
    const int lane = threadIdx.x & 63;
    if (wave >= (long long)NEDGE) return;
    const int b = (int)(wave / N_EDGES);
    const long long ebase = wave * 3;
    const int src = (int)ew[ebase + 0];
    const int dst = (int)ew[ebase + 1];
    const float w = ew[ebase + 2];
    const long long hbase = ((long long)b * N_NODES + dst) * H_SIZE;
    const long long obase = ((long long)b * N_NODES + src) * H_SIZE;
    atomicAdd(&out[obase + lane], w * H[hbase + lane]);
}

extern "C" void kernel_launch(void* const* d_in, const int* in_sizes, int n_in,
                              void* d_out, int out_size, void* d_ws, size_t ws_size,
                              hipStream_t stream) {
    const float* H  = (const float*)d_in[0];   // (B, N, 64) fp32
    const float* ew = (const float*)d_in[1];   // (B, E, 3) fp32
    float* out = (float*)d_out;                // (B, N, 64) fp32

    // Workspace layout (4B elems): cnt[NSEG] | offs[NSEG] | bsum[256] |
    //                              pair[NEDGE] (int2, 8B-aligned)
    const size_t need = ((size_t)NSEG * 2 + 256 + (size_t)NEDGE * 2) * 4;

    if (ws_size < need) {
        long long n = out_size;
        zero_kernel<<<(unsigned)((n + 255) / 256), 256, 0, stream>>>((int*)out, n);
        const long long total = (long long)NEDGE * 64;
        atomic_kernel<<<(unsigned)((total + 255) / 256), 256, 0, stream>>>(H, ew, out);
        return;
    }

    int* cnt  = (int*)d_ws;
    int* offs = cnt + NSEG;
    int* bsum = offs + NSEG;
    int2* pair = (int2*)(bsum + 256);   // offset 1,601,024 B — 8B aligned

    zero_kernel<<<(NSEG + 255) / 256, 256, 0, stream>>>(cnt, NSEG);

    hist_kernel<<<(NEDGE + 255) / 256, 256, 0, stream>>>(ew, cnt);
    scan1_kernel<<<NB1, SCAN_B, 0, stream>>>(cnt, offs, bsum);
    scan2_kernel<<<1, 256, 0, stream>>>(bsum);
    scan3_kernel<<<(NSEG + 255) / 256, 256, 0, stream>>>(offs, bsum);
    scatter_kernel<<<(NEDGE + 255) / 256, 256, 0, stream>>>(ew, offs, pair);

    const long long gthreads = (long long)NSEG * 64;
    gather_kernel<<<(unsigned)((gthreads + 255) / 256), 256, 0, stream>>>(
        H, cnt, offs, pair, out);
}